// Round 3
// baseline (2092.472 us; speedup 1.0000x reference)
//
#include <hip/hip_runtime.h>
#include <hip/hip_bf16.h>
#include <math.h>

#define BB 8
#define NN 4096
#define MM 256
#define NTHREADS 256
#define CPT (NN / NTHREADS) /* 16 columns per thread */

// 5*L1 - 2*IoU, float32, same op structure/order as the jax reference
__device__ __forceinline__ float cost_fn(const float4 p, const float4 t) {
  float l1 = fabsf(p.x - t.x) + fabsf(p.y - t.y) + fabsf(p.z - t.z) + fabsf(p.w - t.w);
  float ltx = fmaxf(p.x, t.x), lty = fmaxf(p.y, t.y);
  float rbx = fminf(p.z, t.z), rby = fminf(p.w, t.w);
  float wx = rbx - ltx; wx = wx > 0.f ? wx : 0.f;
  float wy = rby - lty; wy = wy > 0.f ? wy : 0.f;
  float inter = wx * wy;
  float ap = (p.z - p.x) * (p.w - p.y);
  float at = (t.z - t.x) * (t.w - t.y);
  float un = ap + at - inter;
  float iou = inter / (un + 1e-6f);
  return 5.0f * l1 - 2.0f * iou;
}

// ---------------- cost matrix: one block per (b,n), one thread per m ----------
__global__ void cost_kernel(const float4* __restrict__ pred,
                            const float4* __restrict__ tgt,
                            float* __restrict__ outc) {
  int bn = blockIdx.x;      // b*NN + n
  int m = threadIdx.x;      // 0..255
  int b = bn >> 12;
  float4 p = pred[bn];
  float4 t = tgt[b * MM + m];
  outc[(size_t)bn * MM + m] = cost_fn(p, t);
}

// ---------------- LSA (Jonker-Volgenant shortest augmenting path) -------------
struct LsaShared {
  double v[NN];
  double spc[NN];
  double u[MM];
  double red_val[NTHREADS / 64];
  double s_minval;
  int col4row[MM];
  int red_idx[NTHREADS / 64];
  int s_i;
  int s_sink;
  float tx1[MM], ty1[MM], tx2[MM], ty2[MM];
  short row4col[NN];        // assigned row for each column, -1 = free
  unsigned char path[NN];   // row indices < 256 fit in u8
  unsigned char SC[NN];
  unsigned char sr[MM];
};

__global__ void __launch_bounds__(NTHREADS)
lsa_kernel(const float4* __restrict__ pred, const float4* __restrict__ tgt,
           float* __restrict__ out_pred, float* __restrict__ out_tgt) {
  extern __shared__ char smem_raw[];
  LsaShared& S = *reinterpret_cast<LsaShared*>(smem_raw);
  const int b = blockIdx.x;
  const int t = threadIdx.x;
  const int wid = t >> 6;
  const float4* pb = pred + (size_t)b * NN;

  // ---- init ----
  if (t < MM) {
    float4 tb = tgt[b * MM + t];
    S.tx1[t] = tb.x; S.ty1[t] = tb.y; S.tx2[t] = tb.z; S.ty2[t] = tb.w;
    S.u[t] = 0.0;
    S.col4row[t] = -1;
  }
#pragma unroll
  for (int k = 0; k < CPT; ++k) {
    int j = t + k * NTHREADS;
    S.v[j] = 0.0;
    S.row4col[j] = -1;
  }
  __syncthreads();

  for (int cur = 0; cur < MM; ++cur) {
#pragma unroll
    for (int k = 0; k < CPT; ++k) {
      int j = t + k * NTHREADS;
      S.spc[j] = INFINITY;
      S.SC[j] = 0;
    }
    if (t < MM) S.sr[t] = 0;
    if (t == 0) { S.s_i = cur; S.s_minval = 0.0; S.s_sink = -1; }
    __syncthreads();

    for (;;) {
      const int i = S.s_i;
      const double minval = S.s_minval;
      if (t == 0) S.sr[i] = 1;
      const double u_i = S.u[i];
      const float4 tb = make_float4(S.tx1[i], S.ty1[i], S.tx2[i], S.ty2[i]);
      double bestv = INFINITY;
      int bestj = 0x7fffffff;
#pragma unroll
      for (int k = 0; k < CPT; ++k) {
        int j = t + k * NTHREADS;
        if (S.SC[j]) continue;
        float c = cost_fn(pb[j], tb);
        // numpy op order: ((min_val + cost) - u[i]) - v[j], all double
        double r = ((minval + (double)c) - u_i) - S.v[j];
        double s = S.spc[j];
        if (r < s) { S.spc[j] = r; S.path[j] = (unsigned char)i; s = r; }
        if (s < bestv || (s == bestv && j < bestj)) { bestv = s; bestj = j; }
      }
      // wave argmin (lexicographic (val, idx) => first-min like np.argmin)
#pragma unroll
      for (int off = 32; off > 0; off >>= 1) {
        double ov = __shfl_xor(bestv, off);
        int oj = __shfl_xor(bestj, off);
        if (ov < bestv || (ov == bestv && oj < bestj)) { bestv = ov; bestj = oj; }
      }
      if ((t & 63) == 0) { S.red_val[wid] = bestv; S.red_idx[wid] = bestj; }
      __syncthreads();
      if (t == 0) {
        double mv = S.red_val[0]; int mj = S.red_idx[0];
#pragma unroll
        for (int w = 1; w < NTHREADS / 64; ++w) {
          double ov = S.red_val[w]; int oj = S.red_idx[w];
          if (ov < mv || (ov == mv && oj < mj)) { mv = ov; mj = oj; }
        }
        S.s_minval = mv;
        S.SC[mj] = 1;
        int rc = S.row4col[mj];
        if (rc < 0) S.s_sink = mj; else S.s_i = rc;
      }
      __syncthreads();
      if (S.s_sink >= 0) break;
    }

    // ---- dual updates (before augment, as in reference) ----
    const double minval = S.s_minval;
    if (t < MM && S.sr[t]) {
      if (t == cur) S.u[t] += minval;
      else S.u[t] += minval - S.spc[S.col4row[t]];
    }
#pragma unroll
    for (int k = 0; k < CPT; ++k) {
      int j = t + k * NTHREADS;
      if (S.SC[j]) S.v[j] -= (minval - S.spc[j]);
    }
    __syncthreads();
    // ---- augment along alternating path (serial, thread 0) ----
    if (t == 0) {
      int j = S.s_sink;
      for (;;) {
        int i2 = S.path[j];
        S.row4col[j] = (short)i2;
        int tmp = S.col4row[i2];
        S.col4row[i2] = j;
        j = tmp;
        if (i2 == cur) break;
      }
    }
    __syncthreads();
  }

  // ---- outputs: sort rows by assigned column (argsort of a permutation) ----
  if (t < MM) {
    int myc = S.col4row[t];
    int rank = 0;
    for (int r = 0; r < MM; ++r) rank += (S.col4row[r] < myc) ? 1 : 0;
    out_pred[(size_t)b * MM + rank] = (float)myc;
    out_tgt[(size_t)b * MM + rank] = (float)t;
  }
}

extern "C" void kernel_launch(void* const* d_in, const int* in_sizes, int n_in,
                              void* d_out, int out_size, void* d_ws, size_t ws_size,
                              hipStream_t stream) {
  const float4* pred = (const float4*)d_in[0];   // [B,N,4] f32
  const float4* tgt  = (const float4*)d_in[1];   // [B,M,4] f32
  // d_in[2] = target_mask, all ones in this problem

  float* outc = (float*)d_out;
  float* out_pred = outc + (size_t)BB * NN * MM;
  float* out_tgt = out_pred + (size_t)BB * MM;

  cost_kernel<<<dim3(BB * NN), dim3(MM), 0, stream>>>(pred, tgt, outc);

  (void)hipFuncSetAttribute(reinterpret_cast<const void*>(lsa_kernel),
                            hipFuncAttributeMaxDynamicSharedMemorySize,
                            (int)sizeof(LsaShared));
  lsa_kernel<<<dim3(BB), dim3(NTHREADS), sizeof(LsaShared), stream>>>(
      pred, tgt, out_pred, out_tgt);
}

// Round 4
// 1242.360 us; speedup vs baseline: 1.6843x; 1.6843x over previous
//
#include <hip/hip_runtime.h>
#include <math.h>

#define BB 8
#define NN 4096
#define MM 256
#define NT 256
#define CPT 16   /* contiguous columns per thread: thread t owns [16t, 16t+16) */

// 5*L1 - 2*IoU, float32, same op structure/order as the jax reference
__device__ __forceinline__ float cost_fn(const float4 p, const float4 t) {
  float l1 = fabsf(p.x - t.x) + fabsf(p.y - t.y) + fabsf(p.z - t.z) + fabsf(p.w - t.w);
  float ltx = fmaxf(p.x, t.x), lty = fmaxf(p.y, t.y);
  float rbx = fminf(p.z, t.z), rby = fminf(p.w, t.w);
  float wx = rbx - ltx; wx = wx > 0.f ? wx : 0.f;
  float wy = rby - lty; wy = wy > 0.f ? wy : 0.f;
  float inter = wx * wy;
  float ap = (p.z - p.x) * (p.w - p.y);
  float at = (t.z - t.x) * (t.w - t.y);
  float un = ap + at - inter;
  float iou = inter / (un + 1e-6f);
  return 5.0f * l1 - 2.0f * iou;
}

// cost[b][n][m] -> d_out (reference output 0)
__global__ void cost_kernel(const float4* __restrict__ pred,
                            const float4* __restrict__ tgt,
                            float* __restrict__ outc) {
  int bn = blockIdx.x;
  int m = threadIdx.x;
  int b = bn >> 12;
  outc[(size_t)bn * MM + m] = cost_fn(pred[bn], tgt[b * MM + m]);
}

// costT[b][m][n] -> workspace (transposed layout for coalesced row scans)
__global__ void costT_kernel(const float4* __restrict__ pred,
                             const float4* __restrict__ tgt,
                             float* __restrict__ costT) {
  int bm = blockIdx.x;            // b*MM + m
  int b = bm >> 8;
  float4 tb = tgt[bm];
  const float4* pb = pred + (size_t)b * NN;
  float* out = costT + (size_t)bm * NN;
  int t = threadIdx.x;
#pragma unroll
  for (int k = 0; k < CPT; ++k) {
    int n = t + k * NT;           // coalesced read & write
    out[n] = cost_fn(pb[n], tb);
  }
}

struct LsaShared {
  double u[MM];
  double red_val[2][4];
  int red_idx[2][4];
  int col4row[MM];
  short row4col[NN];
  unsigned char path[NN];
  unsigned char sr[MM];
  float tx1[MM], ty1[MM], tx2[MM], ty2[MM];
};

template <bool USE_T>
__global__ void __launch_bounds__(NT)
lsa_kernel(const float4* __restrict__ pred, const float4* __restrict__ tgt,
           const float* __restrict__ costT,
           float* __restrict__ out_pred, float* __restrict__ out_tgt) {
  __shared__ LsaShared S;
  const int b = blockIdx.x;
  const int t = threadIdx.x;
  const int base = t * CPT;
  const int wid = t >> 6;

  float4 pbox[CPT];               // fallback path only
  if (!USE_T) {
    const float4* pb = pred + (size_t)b * NN;
#pragma unroll
    for (int k = 0; k < CPT; ++k) pbox[k] = pb[base + k];
  }
  {
    float4 tb = tgt[b * MM + t];
    S.tx1[t] = tb.x; S.ty1[t] = tb.y; S.tx2[t] = tb.z; S.ty2[t] = tb.w;
    S.u[t] = 0.0;
    S.col4row[t] = -1;
    S.sr[t] = 0;
  }
  double v_reg[CPT];
#pragma unroll
  for (int k = 0; k < CPT; ++k) { v_reg[k] = 0.0; S.row4col[base + k] = -1; }
  __syncthreads();

  const float* crowT = USE_T ? (costT + (size_t)b * MM * NN) : nullptr;

  for (int cur = 0; cur < MM; ++cur) {
    double spc[CPT];
#pragma unroll
    for (int k = 0; k < CPT; ++k) spc[k] = (double)INFINITY;
    unsigned int scm = 0;         // SC bitmask for owned columns
    int i = cur;
    double minval = 0.0;
    int parity = 0;
    int sink = -1;

    for (;;) {
      if (t == i) S.sr[t] = 1;
      // cost row for current i: issue loads first to overlap with LDS reads
      float c[CPT];
      if (USE_T) {
        const float4* rp = reinterpret_cast<const float4*>(crowT + (size_t)i * NN + base);
        float4 c0 = rp[0], c1 = rp[1], c2 = rp[2], c3 = rp[3];
        c[0] = c0.x; c[1] = c0.y; c[2] = c0.z; c[3] = c0.w;
        c[4] = c1.x; c[5] = c1.y; c[6] = c1.z; c[7] = c1.w;
        c[8] = c2.x; c[9] = c2.y; c[10] = c2.z; c[11] = c2.w;
        c[12] = c3.x; c[13] = c3.y; c[14] = c3.z; c[15] = c3.w;
      } else {
        float4 tb = make_float4(S.tx1[i], S.ty1[i], S.tx2[i], S.ty2[i]);
#pragma unroll
        for (int k = 0; k < CPT; ++k) c[k] = cost_fn(pbox[k], tb);
      }
      double u_i = S.u[i];
      double bestv = (double)INFINITY;
      int bestj = 0x7fffffff;
#pragma unroll
      for (int k = 0; k < CPT; ++k) {
        if ((scm >> k) & 1u) continue;
        // numpy op order: ((min_val + cost) - u[i]) - v[j], all f64
        double r = ((minval + (double)c[k]) - u_i) - v_reg[k];
        if (r < spc[k]) { spc[k] = r; S.path[base + k] = (unsigned char)i; }
        if (spc[k] < bestv) { bestv = spc[k]; bestj = base + k; }  // k asc => first-min
      }
      // wave argmin, lexicographic (val, idx) => global first-occurrence min
#pragma unroll
      for (int off = 32; off > 0; off >>= 1) {
        double ov = __shfl_xor(bestv, off);
        int oj = __shfl_xor(bestj, off);
        if (ov < bestv || (ov == bestv && oj < bestj)) { bestv = ov; bestj = oj; }
      }
      if ((t & 63) == 0) { S.red_val[parity][wid] = bestv; S.red_idx[parity][wid] = bestj; }
      __syncthreads();            // the ONLY barrier per step
      // redundant final reduce in ALL threads (no serial section, no 2nd barrier)
      double mv = S.red_val[parity][0]; int mj = S.red_idx[parity][0];
#pragma unroll
      for (int w = 1; w < 4; ++w) {
        double ov = S.red_val[parity][w]; int oj = S.red_idx[parity][w];
        if (ov < mv || (ov == mv && oj < mj)) { mv = ov; mj = oj; }
      }
      parity ^= 1;
      minval = mv;
      if ((mj >> 4) == t) scm |= (1u << (mj & 15));   // owner marks SC in-register
      int rc = S.row4col[mj];
      if (rc < 0) { sink = mj; break; }
      i = rc;
    }

    // ---- dual updates (column-owner push; row4col injective => race-free) ----
#pragma unroll
    for (int k = 0; k < CPT; ++k) {
      int rc2 = S.row4col[base + k];
      if (rc2 >= 0 && rc2 != cur && S.sr[rc2]) S.u[rc2] += minval - spc[k];
      if ((scm >> k) & 1u) v_reg[k] -= (minval - spc[k]);
    }
    if (t == cur) S.u[t] += minval;
    __syncthreads();
    // ---- augment (short serial walk) ----
    if (t == 0) {
      int j = sink;
      for (;;) {
        int i2 = S.path[j];
        S.row4col[j] = (short)i2;
        int tmp = S.col4row[i2];
        S.col4row[i2] = j;
        j = tmp;
        if (i2 == cur) break;
      }
    }
    __syncthreads();
    S.sr[t] = 0;   // own-slot reset; next reads are after subsequent barriers
  }

  // ---- outputs: argsort of the assignment permutation ----
  {
    int myc = S.col4row[t];
    int rank = 0;
    for (int r = 0; r < MM; ++r) rank += (S.col4row[r] < myc) ? 1 : 0;
    out_pred[(size_t)b * MM + rank] = (float)myc;
    out_tgt[(size_t)b * MM + rank] = (float)t;
  }
}

extern "C" void kernel_launch(void* const* d_in, const int* in_sizes, int n_in,
                              void* d_out, int out_size, void* d_ws, size_t ws_size,
                              hipStream_t stream) {
  const float4* pred = (const float4*)d_in[0];   // [B,N,4] f32
  const float4* tgt  = (const float4*)d_in[1];   // [B,M,4] f32

  float* outc = (float*)d_out;
  float* out_pred = outc + (size_t)BB * NN * MM;
  float* out_tgt = out_pred + (size_t)BB * MM;
  float* costT = (float*)d_ws;
  const size_t needT = (size_t)BB * MM * NN * sizeof(float);  // 33.5 MB

  cost_kernel<<<dim3(BB * NN), dim3(MM), 0, stream>>>(pred, tgt, outc);

  if (ws_size >= needT) {
    costT_kernel<<<dim3(BB * MM), dim3(NT), 0, stream>>>(pred, tgt, costT);
    lsa_kernel<true><<<dim3(BB), dim3(NT), 0, stream>>>(pred, tgt, costT, out_pred, out_tgt);
  } else {
    lsa_kernel<false><<<dim3(BB), dim3(NT), 0, stream>>>(pred, tgt, nullptr, out_pred, out_tgt);
  }
}

// Round 5
// 1152.974 us; speedup vs baseline: 1.8148x; 1.0775x over previous
//
#include <hip/hip_runtime.h>
#include <math.h>

#define BB 8
#define NN 4096
#define MM 256
#define NT 256
#define CPT 16   /* contiguous columns per thread: thread t owns [16t, 16t+16) */

// 5*L1 - 2*IoU, float32, same op structure/order as the jax reference
__device__ __forceinline__ float cost_fn(const float4 p, const float4 t) {
  float l1 = fabsf(p.x - t.x) + fabsf(p.y - t.y) + fabsf(p.z - t.z) + fabsf(p.w - t.w);
  float ltx = fmaxf(p.x, t.x), lty = fmaxf(p.y, t.y);
  float rbx = fminf(p.z, t.z), rby = fminf(p.w, t.w);
  float wx = rbx - ltx; wx = wx > 0.f ? wx : 0.f;
  float wy = rby - lty; wy = wy > 0.f ? wy : 0.f;
  float inter = wx * wy;
  float ap = (p.z - p.x) * (p.w - p.y);
  float at = (t.z - t.x) * (t.w - t.y);
  float un = ap + at - inter;
  float iou = inter / (un + 1e-6f);
  return 5.0f * l1 - 2.0f * iou;
}

// cost[b][n][m] -> d_out (reference output 0)
__global__ void cost_kernel(const float4* __restrict__ pred,
                            const float4* __restrict__ tgt,
                            float* __restrict__ outc) {
  int bn = blockIdx.x;
  int m = threadIdx.x;
  int b = bn >> 12;
  outc[(size_t)bn * MM + m] = cost_fn(pred[bn], tgt[b * MM + m]);
}

// costT[b][m][n] -> workspace (transposed layout for coalesced row scans)
__global__ void costT_kernel(const float4* __restrict__ pred,
                             const float4* __restrict__ tgt,
                             float* __restrict__ costT) {
  int bm = blockIdx.x;            // b*MM + m
  int b = bm >> 8;
  float4 tb = tgt[bm];
  const float4* pb = pred + (size_t)b * NN;
  float* out = costT + (size_t)bm * NN;
  int t = threadIdx.x;
#pragma unroll
  for (int k = 0; k < CPT; ++k) {
    int n = t + k * NT;           // coalesced read & write
    out[n] = cost_fn(pb[n], tb);
  }
}

struct LsaShared {
  double u[MM];
  double redv[2][4];
  short row4col[NN];              // col -> assigned row, -1 free
  unsigned pathw[4 * MM];         // packed path bytes, transposed [q][t]
  int col4row[MM];
  unsigned redp[2][4];
  float tx1[MM], ty1[MM], tx2[MM], ty2[MM];
  unsigned char sr[MM];
};

template <bool USE_T>
__global__ void __launch_bounds__(NT, 1)
lsa_kernel(const float4* __restrict__ pred, const float4* __restrict__ tgt,
           const float* __restrict__ costT,
           float* __restrict__ out_pred, float* __restrict__ out_tgt) {
  __shared__ LsaShared S;
  const int b = blockIdx.x;
  const int t = threadIdx.x;
  const int base = t * CPT;
  const int wid = t >> 6;

  float4 pbox[CPT];               // fallback path only
  if (!USE_T) {
    const float4* pb = pred + (size_t)b * NN;
#pragma unroll
    for (int k = 0; k < CPT; ++k) pbox[k] = pb[base + k];
  }
  {
    float4 tb = tgt[b * MM + t];
    S.tx1[t] = tb.x; S.ty1[t] = tb.y; S.tx2[t] = tb.z; S.ty2[t] = tb.w;
    S.u[t] = 0.0;
    S.col4row[t] = -1;
    S.sr[t] = 0;
  }
  int* r4c_i = reinterpret_cast<int*>(S.row4col);
#pragma unroll
  for (int q = 0; q < CPT / 2; ++q) r4c_i[t * (CPT / 2) + q] = (int)0xFFFFFFFF;

  double v_reg[CPT];
  int rc_reg[CPT];                // row4col snapshot for owned cols (static per augment)
  unsigned pay[CPT];              // (col<<9) | (rc+1)  (idx high => lexicographic)
  unsigned path_reg[CPT];
#pragma unroll
  for (int k = 0; k < CPT; ++k) {
    v_reg[k] = 0.0; rc_reg[k] = -1;
    pay[k] = ((unsigned)(base + k) << 9);
    path_reg[k] = 0;              // matches reference: path persists across augments
  }
  __syncthreads();

  const float* crowT = USE_T ? (costT + (size_t)b * MM * NN) : nullptr;

  for (int cur = 0; cur < MM; ++cur) {
    double spc[CPT];
#pragma unroll
    for (int k = 0; k < CPT; ++k) spc[k] = (double)INFINITY;
    unsigned scm = 0;             // SC bitmask for owned columns
    int i = cur;
    double minval = 0.0;
    int parity = 0;
    int sink = -1;

    for (;;) {
      if (t == i) S.sr[t] = 1;
      // issue cost-row load + u_i read as early as possible (i known at loop top)
      float c[CPT];
      if (USE_T) {
        const float4* rp = reinterpret_cast<const float4*>(crowT + (size_t)i * NN + base);
        float4 c0 = rp[0], c1 = rp[1], c2 = rp[2], c3 = rp[3];
        c[0] = c0.x; c[1] = c0.y; c[2] = c0.z; c[3] = c0.w;
        c[4] = c1.x; c[5] = c1.y; c[6] = c1.z; c[7] = c1.w;
        c[8] = c2.x; c[9] = c2.y; c[10] = c2.z; c[11] = c2.w;
        c[12] = c3.x; c[13] = c3.y; c[14] = c3.z; c[15] = c3.w;
      } else {
        float4 tb = make_float4(S.tx1[i], S.ty1[i], S.tx2[i], S.ty2[i]);
#pragma unroll
        for (int k = 0; k < CPT; ++k) c[k] = cost_fn(pbox[k], tb);
      }
      double u_i = S.u[i];
      double bestv = (double)INFINITY;
      unsigned bestp = 0xFFFFFFFFu;
#pragma unroll
      for (int k = 0; k < CPT; ++k) {
        bool open = !((scm >> k) & 1u);
        // numpy op order: ((min_val + cost) - u[i]) - v[j], all f64
        double r = ((minval + (double)c[k]) - u_i) - v_reg[k];
        if (open && r < spc[k]) { spc[k] = r; path_reg[k] = (unsigned)i; }
        if (open && spc[k] < bestv) { bestv = spc[k]; bestp = pay[k]; }  // k asc => first-min
      }
      // wave argmin: lexicographic (val, pay); pay has idx in high bits
#pragma unroll
      for (int off = 1; off <= 32; off <<= 1) {
        double ov = __shfl_xor(bestv, off);
        unsigned op = __shfl_xor(bestp, off);
        if (ov < bestv || (ov == bestv && op < bestp)) { bestv = ov; bestp = op; }
      }
      if ((t & 63) == 0) { S.redv[parity][wid] = bestv; S.redp[parity][wid] = bestp; }
      __syncthreads();            // the only barrier per step
      double mv = S.redv[parity][0]; unsigned mp = S.redp[parity][0];
#pragma unroll
      for (int w = 1; w < 4; ++w) {
        double ov = S.redv[parity][w]; unsigned op = S.redp[parity][w];
        if (ov < mv || (ov == mv && op < mp)) { mv = ov; mp = op; }
      }
      parity ^= 1;
      minval = mv;
      int mj = (int)(mp >> 9);
      int rc = (int)(mp & 511u) - 1;        // row4col[mj], carried through the reduce
      if ((mj >> 4) == t) scm |= (1u << (mj & 15));
      if (rc < 0) { sink = mj; break; }
      i = rc;
    }

    // ---- dual updates (column-owner push; row4col injective => race-free) ----
#pragma unroll
    for (int k = 0; k < CPT; ++k) {
      int rc2 = rc_reg[k];
      if (rc2 >= 0 && rc2 != cur && S.sr[rc2]) S.u[rc2] += minval - spc[k];
      if ((scm >> k) & 1u) v_reg[k] -= (minval - spc[k]);
    }
    if (t == cur) S.u[t] += minval;
    // ---- publish path registers (transposed words: conflict-free stride-4B) ----
#pragma unroll
    for (int q = 0; q < 4; ++q) {
      unsigned w = (path_reg[4 * q] & 255u) | ((path_reg[4 * q + 1] & 255u) << 8) |
                   ((path_reg[4 * q + 2] & 255u) << 16) | ((path_reg[4 * q + 3] & 255u) << 24);
      S.pathw[q * MM + t] = w;
    }
    __syncthreads();
    // ---- augment along alternating path (short serial walk) ----
    if (t == 0) {
      int j = sink;
      for (;;) {
        unsigned w = S.pathw[((j >> 2) & 3) * MM + (j >> 4)];
        int i2 = (int)((w >> ((j & 3) * 8)) & 255u);
        S.row4col[j] = (short)i2;
        int tmp = S.col4row[i2];
        S.col4row[i2] = j;
        j = tmp;
        if (i2 == cur) break;
      }
    }
    __syncthreads();
    S.sr[t] = 0;   // own-slot reset
    // ---- refresh row4col snapshot + pay for owned cols (8 int LDS reads) ----
#pragma unroll
    for (int q = 0; q < CPT / 2; ++q) {
      int w = r4c_i[t * (CPT / 2) + q];
      int r0 = (int)(short)(w & 0xFFFF);
      int r1 = (w >> 16);                  // arithmetic shift sign-extends
      rc_reg[2 * q] = r0;
      rc_reg[2 * q + 1] = r1;
      pay[2 * q] = ((unsigned)(base + 2 * q) << 9) | (unsigned)(r0 + 1);
      pay[2 * q + 1] = ((unsigned)(base + 2 * q + 1) << 9) | (unsigned)(r1 + 1);
    }
  }

  // ---- outputs: argsort of the assignment permutation ----
  {
    int myc = S.col4row[t];
    int rank = 0;
    for (int r = 0; r < MM; ++r) rank += (S.col4row[r] < myc) ? 1 : 0;
    out_pred[(size_t)b * MM + rank] = (float)myc;
    out_tgt[(size_t)b * MM + rank] = (float)t;
  }
}

extern "C" void kernel_launch(void* const* d_in, const int* in_sizes, int n_in,
                              void* d_out, int out_size, void* d_ws, size_t ws_size,
                              hipStream_t stream) {
  const float4* pred = (const float4*)d_in[0];   // [B,N,4] f32
  const float4* tgt  = (const float4*)d_in[1];   // [B,M,4] f32

  float* outc = (float*)d_out;
  float* out_pred = outc + (size_t)BB * NN * MM;
  float* out_tgt = out_pred + (size_t)BB * MM;
  float* costT = (float*)d_ws;
  const size_t needT = (size_t)BB * MM * NN * sizeof(float);  // 33.5 MB

  cost_kernel<<<dim3(BB * NN), dim3(MM), 0, stream>>>(pred, tgt, outc);

  if (ws_size >= needT) {
    costT_kernel<<<dim3(BB * MM), dim3(NT), 0, stream>>>(pred, tgt, costT);
    lsa_kernel<true><<<dim3(BB), dim3(NT), 0, stream>>>(pred, tgt, costT, out_pred, out_tgt);
  } else {
    lsa_kernel<false><<<dim3(BB), dim3(NT), 0, stream>>>(pred, tgt, nullptr, out_pred, out_tgt);
  }
}